// Round 5
// baseline (88.068 us; speedup 1.0000x reference)
//
#include <hip/hip_runtime.h>

// NCF fused forward, v5: software-pipelined item gather.
//  ncf_prep : blocks 0..B-1 (128 thr): Xu[b] = b1 + (eu_m+bu_m)@W1u + bi_mlp@W1i (f32),
//             wup[b] = (eu_g+bu_g).*Wp[0:64], cu[b] = wup[b].bi_gmf
//             blocks B.. : W1iT/W2T/W3T transposes to bf16 [out][in]
//  ncf_main : persistent (grid 1024), 64 pairs/tile. Pipeline per tile:
//             flush(prev out) + consume prefetched rows -> LDS | bar |
//             issue next tile's row loads | GEMM1 K=64 (+Xu) | bar |
//             GEMM2 K=128 | bar | GEMM3 K=64 -> s_h3 | bar.

typedef __attribute__((ext_vector_type(8))) short bf16x8;
typedef __attribute__((ext_vector_type(4))) float f32x4;

__device__ __forceinline__ short f2bf(float x){
  unsigned u = __float_as_uint(x);
  u += 0x7fffu + ((u >> 16) & 1u);
  return (short)(u >> 16);
}
__device__ __forceinline__ float bf2f(short s){
  return __uint_as_float(((unsigned)(unsigned short)s) << 16);
}

// ws layout (bytes):
//   0      W1iT bf16 [128][64]   (16384)
//   16384  W2T  bf16 [64][128]   (16384)
//   32768  W3T  bf16 [32][64]    (4096)
//   36864  Xu   f32  [B][128]
//   then   wup  f32  [B][64],  cu f32 [B]

__global__ __launch_bounds__(128) void ncf_prep(
    const int* __restrict__ user,
    const float* __restrict__ Wu_gmf, const float* __restrict__ bu_gmf,
    const float* __restrict__ Wu_mlp, const float* __restrict__ bu_mlp,
    const float* __restrict__ bi_gmf, const float* __restrict__ bi_mlp,
    const float* __restrict__ W1, const float* __restrict__ b1,
    const float* __restrict__ W2, const float* __restrict__ W3,
    const float* __restrict__ Wp,
    short* __restrict__ wsT, float* __restrict__ Xu,
    float* __restrict__ wup, float* __restrict__ cu, int B)
{
  int bid = blockIdx.x;
  int j = threadIdx.x;
  if (bid < B){
    long u = (long)user[bid];
    float acc = b1[j];
    #pragma unroll 4
    for (int k = 0; k < 64; k++){
      float eu = Wu_mlp[u*64 + k] + bu_mlp[k];
      acc += eu * W1[k*128 + j] + bi_mlp[k] * W1[(64 + k)*128 + j];
    }
    Xu[(long)bid*128 + j] = acc;
    if (j < 64){
      float wg = (Wu_gmf[u*64 + j] + bu_gmf[j]) * Wp[j];
      wup[(long)bid*64 + j] = wg;
      float c = wg * bi_gmf[j];
      c += __shfl_xor(c, 1);  c += __shfl_xor(c, 2);
      c += __shfl_xor(c, 4);  c += __shfl_xor(c, 8);
      c += __shfl_xor(c, 16); c += __shfl_xor(c, 32);
      if (j == 0) cu[bid] = c;
    }
    return;
  }
  int i = (bid - B)*128 + j;                    // 0..18431
  if (i < 8192){                                // W1iT[col][k] = W1[64+k][col]
    int col = i >> 6, k = i & 63;
    wsT[i] = f2bf(W1[(64 + k)*128 + col]);
  } else if (i < 16384){                        // W2T[col][k] = W2[k][col]
    int t = i - 8192; int col = t >> 7, k = t & 127;
    wsT[i] = f2bf(W2[k*64 + col]);
  } else if (i < 18432){                        // W3T[col][k] = W3[k][col]
    int t = i - 16384; int col = t >> 6, k = t & 63;
    wsT[i] = f2bf(W3[k*32 + col]);
  }
}

__global__ __launch_bounds__(256) void ncf_main(
    const int* __restrict__ item,
    const float* __restrict__ Wi_mlp, const float* __restrict__ Wi_gmf,
    const short* __restrict__ W1iT, const short* __restrict__ W2T,
    const short* __restrict__ W3T,
    const float* __restrict__ b2, const float* __restrict__ b3,
    const float* __restrict__ Wp, const float* __restrict__ bp,
    const float* __restrict__ Xu, const float* __restrict__ wup,
    const float* __restrict__ cu,
    float* __restrict__ out, int N, int total, int ntiles, int Bsz)
{
  __shared__ __align__(16) short s_item[64][72];   // item mlp rows; reused as h2
  __shared__ __align__(16) short s_h1[64][136];
  __shared__ __align__(16) short s_h3[64][34];
  __shared__ __align__(16) float s_xu[2][128];

  const int tid = threadIdx.x;
  const int r  = tid >> 2, q = tid & 3;
  const int w  = tid >> 6, l = tid & 63;
  const int lr = l & 15,  lg = l >> 4;
  const int G  = gridDim.x;

  // ---- prologue: prefetch tile t0's item rows + t1's index ----
  float4 im[4], ig[4];
  int idx_next = 0;
  {
    int p = blockIdx.x*64 + r;
    long ib = (long)item[p] * 64;
    const float4* imp = (const float4*)(Wi_mlp + ib) + q*4;
    const float4* igp = (const float4*)(Wi_gmf + ib) + q*4;
    #pragma unroll
    for (int jj = 0; jj < 4; jj++){ im[jj] = imp[jj]; ig[jj] = igp[jj]; }
    int t1 = blockIdx.x + G;
    if (t1 < ntiles) idx_next = item[t1*64 + r];
  }

  float pg_reg = 0.f;       // valid on q==0 lanes after each store phase
  int prev_p0 = -1;

  for (int t = blockIdx.x; t < ntiles; t += G){
    const int p0  = t * 64;
    const int b0  = p0 / N;
    const int thr = (b0 + 1) * N;

    // ---- flush previous tile's output (reads s_h3 of prev iter) ----
    if (prev_p0 >= 0){
      float sum = 0.f;
      #pragma unroll
      for (int i = 0; i < 8; i++){
        int c = q*8 + i;
        sum += bf2f(s_h3[r][c]) * Wp[64 + c];
      }
      sum += __shfl_xor(sum, 1);
      sum += __shfl_xor(sum, 2);
      if (q == 0){
        float z = pg_reg + sum + bp[0];
        out[prev_p0 + r] = 1.f / (1.f + __expf(-z));
      }
    }

    // ---- store phase: consume prefetched rows; pg dot; stage Xu ----
    {
      int p = p0 + r;
      int b = b0 + ((p >= thr) ? 1 : 0);
      const float4* wq = (const float4*)(wup + (long)b*64) + q*4;
      bf16x8 ia[2];
      float pg = 0.f;
      #pragma unroll
      for (int jj = 0; jj < 4; jj++){
        float4 v = im[jj];
        float4 g = ig[jj];
        float4 wv = wq[jj];
        pg += g.x*wv.x + g.y*wv.y + g.z*wv.z + g.w*wv.w;
        int h = jj >> 1, s = (jj & 1) * 4;
        ia[h][s+0] = f2bf(v.x); ia[h][s+1] = f2bf(v.y);
        ia[h][s+2] = f2bf(v.z); ia[h][s+3] = f2bf(v.w);
      }
      *(bf16x8*)&s_item[r][q*16]     = ia[0];
      *(bf16x8*)&s_item[r][q*16 + 8] = ia[1];
      pg += __shfl_xor(pg, 1);
      pg += __shfl_xor(pg, 2);
      if (q == 0) pg_reg = pg + cu[b];
      int i2 = tid >> 7, col = tid & 127;
      int bb = b0 + i2; if (bb >= Bsz) bb = Bsz - 1;
      s_xu[i2][col] = Xu[(long)bb*128 + col];
      prev_p0 = p0;
    }
    __syncthreads();

    // ---- issue next tile's row loads (fly during GEMMs) + next-next index ----
    if (t + G < ntiles){
      long ib = (long)idx_next * 64;
      const float4* imp = (const float4*)(Wi_mlp + ib) + q*4;
      const float4* igp = (const float4*)(Wi_gmf + ib) + q*4;
      #pragma unroll
      for (int jj = 0; jj < 4; jj++){ im[jj] = imp[jj]; ig[jj] = igp[jj]; }
      if (t + 2*G < ntiles) idx_next = item[(t + 2*G)*64 + r];
    }

    // ---- GEMM1: h1 = relu(item @ W1i + Xu[b]), K=64 ----
    {
      f32x4 acc[4][2];
      #pragma unroll
      for (int mt = 0; mt < 4; mt++)
        #pragma unroll
        for (int nt = 0; nt < 2; nt++)
          acc[mt][nt] = (f32x4){0.f, 0.f, 0.f, 0.f};
      #pragma unroll
      for (int ks = 0; ks < 2; ks++){
        bf16x8 af[4];
        #pragma unroll
        for (int mt = 0; mt < 4; mt++)
          af[mt] = *(const bf16x8*)&s_item[mt*16 + lr][ks*32 + lg*8];
        #pragma unroll
        for (int nt = 0; nt < 2; nt++){
          bf16x8 bfg = *(const bf16x8*)&W1iT[(w*32 + nt*16 + lr)*64 + ks*32 + lg*8];
          #pragma unroll
          for (int mt = 0; mt < 4; mt++)
            acc[mt][nt] = __builtin_amdgcn_mfma_f32_16x16x32_bf16(af[mt], bfg, acc[mt][nt], 0, 0, 0);
        }
      }
      #pragma unroll
      for (int nt = 0; nt < 2; nt++){
        int col = w*32 + nt*16 + lr;
        #pragma unroll
        for (int mt = 0; mt < 4; mt++)
          #pragma unroll
          for (int rr = 0; rr < 4; rr++){
            int row = mt*16 + lg*4 + rr;
            int bl = (p0 + row >= thr) ? 1 : 0;
            float v = acc[mt][nt][rr] + s_xu[bl][col];
            s_h1[row][col] = f2bf(v > 0.f ? v : 0.f);
          }
      }
    }
    __syncthreads();

    // ---- GEMM2: h2 = relu(h1 @ W2 + b2) -> s_item cols 0..63 ----
    {
      f32x4 acc2[4];
      #pragma unroll
      for (int mt = 0; mt < 4; mt++) acc2[mt] = (f32x4){0.f, 0.f, 0.f, 0.f};
      #pragma unroll
      for (int ks = 0; ks < 4; ks++){
        bf16x8 bfg = *(const bf16x8*)&W2T[(w*16 + lr)*128 + ks*32 + lg*8];
        #pragma unroll
        for (int mt = 0; mt < 4; mt++){
          bf16x8 a = *(const bf16x8*)&s_h1[mt*16 + lr][ks*32 + lg*8];
          acc2[mt] = __builtin_amdgcn_mfma_f32_16x16x32_bf16(a, bfg, acc2[mt], 0, 0, 0);
        }
      }
      int col = w*16 + lr;
      float bb = b2[col];
      #pragma unroll
      for (int mt = 0; mt < 4; mt++)
        #pragma unroll
        for (int rr = 0; rr < 4; rr++){
          int row = mt*16 + lg*4 + rr;
          float v = acc2[mt][rr] + bb;
          s_item[row][col] = f2bf(v > 0.f ? v : 0.f);
        }
    }
    __syncthreads();

    // ---- GEMM3: h3 = relu(h2 @ W3 + b3) -> s_h3 (waves 0,1) ----
    if (w < 2){
      f32x4 acc3[4];
      #pragma unroll
      for (int mt = 0; mt < 4; mt++) acc3[mt] = (f32x4){0.f, 0.f, 0.f, 0.f};
      #pragma unroll
      for (int ks = 0; ks < 2; ks++){
        bf16x8 bfg = *(const bf16x8*)&W3T[(w*16 + lr)*64 + ks*32 + lg*8];
        #pragma unroll
        for (int mt = 0; mt < 4; mt++){
          bf16x8 a = *(const bf16x8*)&s_item[mt*16 + lr][ks*32 + lg*8];
          acc3[mt] = __builtin_amdgcn_mfma_f32_16x16x32_bf16(a, bfg, acc3[mt], 0, 0, 0);
        }
      }
      int col = w*16 + lr;
      float bb = b3[col];
      #pragma unroll
      for (int mt = 0; mt < 4; mt++)
        #pragma unroll
        for (int rr = 0; rr < 4; rr++){
          int row = mt*16 + lg*4 + rr;
          float v = acc3[mt][rr] + bb;
          s_h3[row][col] = f2bf(v > 0.f ? v : 0.f);
        }
    }
    __syncthreads();   // s_h3 ready; also protects s_item/s_xu for next store
  }

  // ---- epilogue: flush last tile ----
  if (prev_p0 >= 0){
    float sum = 0.f;
    #pragma unroll
    for (int i = 0; i < 8; i++){
      int c = q*8 + i;
      sum += bf2f(s_h3[r][c]) * Wp[64 + c];
    }
    sum += __shfl_xor(sum, 1);
    sum += __shfl_xor(sum, 2);
    if (q == 0){
      float z = pg_reg + sum + bp[0];
      out[prev_p0 + r] = 1.f / (1.f + __expf(-z));
    }
  }
}

extern "C" void kernel_launch(void* const* d_in, const int* in_sizes, int n_in,
                              void* d_out, int out_size, void* d_ws, size_t ws_size,
                              hipStream_t stream)
{
  const int*   user   = (const int*)  d_in[0];
  const int*   item   = (const int*)  d_in[1];
  const float* Wu_gmf = (const float*)d_in[3];
  const float* bu_gmf = (const float*)d_in[4];
  const float* Wu_mlp = (const float*)d_in[5];
  const float* bu_mlp = (const float*)d_in[6];
  const float* Wi_gmf = (const float*)d_in[7];
  const float* bi_gmf = (const float*)d_in[8];
  const float* Wi_mlp = (const float*)d_in[9];
  const float* bi_mlp = (const float*)d_in[10];
  const float* W1     = (const float*)d_in[11];
  const float* b1     = (const float*)d_in[12];
  const float* W2     = (const float*)d_in[13];
  const float* b2     = (const float*)d_in[14];
  const float* W3     = (const float*)d_in[15];
  const float* b3     = (const float*)d_in[16];
  const float* Wp     = (const float*)d_in[17];
  const float* bp     = (const float*)d_in[18];

  int B     = in_sizes[0];            // 4096
  int total = in_sizes[1];            // 409600
  int N     = total / B;              // 100

  char* wsb = (char*)d_ws;
  short* W1iT = (short*)wsb;                     // [128][64]
  short* W2T  = (short*)(wsb + 16384);           // [64][128]
  short* W3T  = (short*)(wsb + 32768);           // [32][64]
  float* Xu   = (float*)(wsb + 36864);           // B*128
  float* wup  = Xu  + (size_t)B * 128;           // B*64
  float* cuv  = wup + (size_t)B * 64;            // B

  ncf_prep<<<B + 144, 128, 0, stream>>>(user, Wu_gmf, bu_gmf, Wu_mlp, bu_mlp,
                                        bi_gmf, bi_mlp, W1, b1, W2, W3, Wp,
                                        (short*)d_ws, Xu, wup, cuv, B);

  int ntiles = (total + 63) / 64;     // 6400
  ncf_main<<<1024, 256, 0, stream>>>(item, Wi_mlp, Wi_gmf,
      W1iT, W2T, W3T, b2, b3, Wp, bp, Xu, wup, cuv,
      (float*)d_out, N, total, ntiles, B);
}